// Round 2
// baseline (330.681 us; speedup 1.0000x reference)
//
#include <hip/hip_runtime.h>
#include <math.h>

#define B_   16
#define N_   16384
#define LOGN 14
#define CIN  64
#define COUT 64
#define T_   256
#define M_   2049

__device__ __forceinline__ unsigned br14(unsigned v) {
  return __brev(v) >> 18;   // 14-bit reversal
}

// XOR bank swizzle: bank(n) = (n ^ n>>5 ^ n>>10) & 31. Bijective per 32-block.
__device__ __forceinline__ int SW(int n) {
  return (n & ~31) | ((n ^ (n >> 5) ^ (n >> 10)) & 31);
}

__device__ __forceinline__ void cmul(float ar, float ai, float br, float bi,
                                     float& rr, float& ri) {
  rr = ar * br - ai * bi;
  ri = ar * bi + ai * br;
}

// cos/sin of 2*pi*m/16
__device__ __constant__ float C16[16] = {
  1.f, 0.92387953251f, 0.70710678119f, 0.38268343236f, 0.f, -0.38268343236f,
  -0.70710678119f, -0.92387953251f, -1.f, -0.92387953251f, -0.70710678119f,
  -0.38268343236f, 0.f, 0.38268343236f, 0.70710678119f, 0.92387953251f};
__device__ __constant__ float S16[16] = {
  0.f, 0.38268343236f, 0.70710678119f, 0.92387953251f, 1.f, 0.92387953251f,
  0.70710678119f, 0.38268343236f, 0.f, -0.38268343236f, -0.70710678119f,
  -0.92387953251f, -1.f, -0.92387953251f, -0.70710678119f, -0.38268343236f};

// One radix-16 group = 4 radix-2 DIT substages done in registers.
// Works for any FFT length: covers points base + j<<S0 for j=0..15.
template <int SIGN, int S0>
__device__ __forceinline__ void group16(float* __restrict__ sre,
                                        float* __restrict__ sim, int tid) {
  const int lo = tid & ((1 << S0) - 1);
  const int hi = tid >> S0;
  const int base = (hi << (S0 + 4)) + lo;
  int pp[16];
  float xr[16], xi[16];
#pragma unroll
  for (int j = 0; j < 16; ++j) {
    pp[j] = SW(base + (j << S0));
    xr[j] = sre[pp[j]];
    xi[j] = sim[pp[j]];
  }
  float th = 6.283185307179586f * (float)lo / (float)(16 << S0);
  float sn, cs;
  __sincosf(th, &sn, &cs);
  float w1r = cs, w1i = (float)SIGN * sn;
  float w2r, w2i, w4r, w4i, w8r, w8i;
  cmul(w1r, w1i, w1r, w1i, w2r, w2i);
  cmul(w2r, w2i, w2r, w2i, w4r, w4i);
  cmul(w4r, w4i, w4r, w4i, w8r, w8i);
  {
#pragma unroll
    for (int j = 0; j < 16; j += 2) {
      float br, bi;
      cmul(xr[j + 1], xi[j + 1], w8r, w8i, br, bi);
      xr[j + 1] = xr[j] - br; xi[j + 1] = xi[j] - bi;
      xr[j] += br; xi[j] += bi;
    }
  }
  {
    float tr[2], ti[2];
    tr[0] = w4r; ti[0] = w4i;
    cmul(w4r, w4i, C16[4], (float)SIGN * S16[4], tr[1], ti[1]);
#pragma unroll
    for (int j = 0; j < 16; ++j) {
      if ((j & 2) == 0) {
        int jl = j & 1;
        float br, bi;
        cmul(xr[j + 2], xi[j + 2], tr[jl], ti[jl], br, bi);
        xr[j + 2] = xr[j] - br; xi[j + 2] = xi[j] - bi;
        xr[j] += br; xi[j] += bi;
      }
    }
  }
  {
    float tr[4], ti[4];
#pragma unroll
    for (int jl = 0; jl < 4; ++jl)
      cmul(w2r, w2i, C16[2 * jl], (float)SIGN * S16[2 * jl], tr[jl], ti[jl]);
#pragma unroll
    for (int j = 0; j < 16; ++j) {
      if ((j & 4) == 0) {
        int jl = j & 3;
        float br, bi;
        cmul(xr[j + 4], xi[j + 4], tr[jl], ti[jl], br, bi);
        xr[j + 4] = xr[j] - br; xi[j + 4] = xi[j] - bi;
        xr[j] += br; xi[j] += bi;
      }
    }
  }
  {
    float tr[8], ti[8];
#pragma unroll
    for (int jl = 0; jl < 8; ++jl)
      cmul(w1r, w1i, C16[jl], (float)SIGN * S16[jl], tr[jl], ti[jl]);
#pragma unroll
    for (int j = 0; j < 8; ++j) {
      float br, bi;
      cmul(xr[j + 8], xi[j + 8], tr[j], ti[j], br, bi);
      xr[j + 8] = xr[j] - br; xi[j + 8] = xi[j] - bi;
      xr[j] += br; xi[j] += bi;
    }
  }
#pragma unroll
  for (int j = 0; j < 16; ++j) {
    sre[pp[j]] = xr[j];
    sim[pp[j]] = xi[j];
  }
}

// Radix-2 stage, span 4096, N=16384. 1024 threads x 8 butterflies.
template <int SIGN>
__device__ __forceinline__ void stage12(float* __restrict__ sre,
                                        float* __restrict__ sim, int tid) {
  const int lo0 = tid & 511;
  const int gg  = tid >> 9;     // which 8192-half
  float th = 6.283185307179586f * (float)lo0 / 8192.0f;
  float sn, cs;
  __sincosf(th, &sn, &cs);
  float wtr = cs, wti = (float)SIGN * sn;
#pragma unroll
  for (int s = 0; s < 8; ++s) {
    float twr, twi;
    cmul(wtr, wti, C16[s], (float)SIGN * S16[s], twr, twi);  // W_8192^(lo0+512s)
    int lo = lo0 + 512 * s;
    int i0 = (gg << 13) + lo;
    int p0 = SW(i0), p1 = SW(i0 + 4096);
    float br, bi;
    cmul(sre[p1], sim[p1], twr, twi, br, bi);
    float ar = sre[p0], ai = sim[p0];
    sre[p0] = ar + br; sim[p0] = ai + bi;
    sre[p1] = ar - br; sim[p1] = ai - bi;
  }
}

// Final radix-2 stage, span 8192, N=16384. 1024 threads x 8 butterflies.
template <int SIGN>
__device__ __forceinline__ void stage13(float* __restrict__ sre,
                                        float* __restrict__ sim, int tid) {
  float th = 6.283185307179586f * (float)tid / 16384.0f;
  float sn, cs;
  __sincosf(th, &sn, &cs);
  float wtr = cs, wti = (float)SIGN * sn;
#pragma unroll
  for (int s = 0; s < 8; ++s) {
    float twr, twi;
    cmul(wtr, wti, C16[s], (float)SIGN * S16[s], twr, twi);  // W_16384^(tid+1024s)
    int i0 = tid + 1024 * s;          // 0..8191
    int p0 = SW(i0), p1 = SW(i0 + 8192);
    float br, bi;
    cmul(sre[p1], sim[p1], twr, twi, br, bi);
    float ar = sre[p0], ai = sim[p0];
    sre[p0] = ar + br; sim[p0] = ai + bi;
    sre[p1] = ar - br; sim[p1] = ai - bi;
  }
}

// Grid swizzle for the fused FFT kernels (512 blocks = 16 b x 32 ch-pairs).
// All 8 blocks sharing a 64B line of x/out (same b, same 16-channel group)
// get ids == p (mod 8) -> same XCD, within one 64-id window -> co-resident.
__device__ __forceinline__ void decode_bc(int id, int& b, int& cp) {
  int q = id >> 6, r = (id >> 3) & 7, p = id & 7;
  int g = q * 8 + p;          // 0..63 = (b, cpg)
  b  = g >> 2;
  cp = (g & 3) * 8 + r;       // channel pair 0..31
}

// ---------------- Kernel A: t_mod = t_emb @ dense^T (complex) ----------------
__global__ __launch_bounds__(256) void tmod_kernel(
    const float* __restrict__ t_emb,
    const float* __restrict__ dwr, const float* __restrict__ dwi,
    float* __restrict__ tmr, float* __restrict__ tmi) {
  int wave = threadIdx.x >> 6;
  int lane = threadIdx.x & 63;
  int p = blockIdx.x * 4 + wave;
  if (p >= B_ * M_) return;
  int b = p / M_, i = p % M_;
  float ar = 0.f, ai = 0.f;
  for (int j = 0; j < 4; ++j) {
    int t = lane + 64 * j;
    float te = t_emb[b * T_ + t];
    ar += te * dwr[(size_t)i * T_ + t];
    ai += te * dwi[(size_t)i * T_ + t];
  }
  for (int off = 32; off > 0; off >>= 1) {
    ar += __shfl_down(ar, off, 64);
    ai += __shfl_down(ai, off, 64);
  }
  if (lane == 0) { tmr[b * M_ + i] = ar; tmi[b * M_ + i] = ai; }
}

// ------- Kernel B: fused load + 16384-pt FFT of channel pair + rfft split ----
// z[n] = x[b,n,c0] + i*x[b,n,c0+1]; Z = FFT_16384(z);
// X_c0[k] = (Z[k]+conj(Z[N-k]))/2 ; X_c1[k] = -i/2*(Z[k]-conj(Z[N-k]))
__global__ __launch_bounds__(1024) void fft_fwd_fused(
    const float* __restrict__ x,
    float* __restrict__ Xre, float* __restrict__ Xim) {
  __shared__ float sre[N_], sim[N_];    // 128 KiB
  int b, cp;
  decode_bc(blockIdx.x, b, cp);
  const int tid = threadIdx.x;
  const float* xb = x + (size_t)b * N_ * CIN + 2 * cp;
  float2 v[16];
#pragma unroll
  for (int s = 0; s < 16; ++s) {
    int n = tid + 1024 * s;
    v[s] = *(const float2*)(xb + (size_t)n * CIN);
  }
#pragma unroll
  for (int s = 0; s < 16; ++s) {
    int n = tid + 1024 * s;
    int rr = SW((int)br14((unsigned)n));
    sre[rr] = v[s].x;
    sim[rr] = v[s].y;
  }
  __syncthreads();
  group16<-1, 0>(sre, sim, tid); __syncthreads();
  group16<-1, 4>(sre, sim, tid); __syncthreads();
  group16<-1, 8>(sre, sim, tid); __syncthreads();
  stage12<-1>(sre, sim, tid);    __syncthreads();
  stage13<-1>(sre, sim, tid);    __syncthreads();
  const float sc = 1.0f / (float)N_;   // norm='forward'
  size_t o0 = (size_t)(b * CIN + 2 * cp) * M_;
  size_t o1 = o0 + M_;
  for (int k = tid; k < M_; k += 1024) {
    int mk = (N_ - k) & (N_ - 1);
    int pk = SW(k), pm = SW(mk);
    float zr = sre[pk], zi = sim[pk];
    float mr = sre[pm], mi = sim[pm];
    float X0r = 0.5f * (zr + mr), X0i = 0.5f * (zi - mi);
    float X1r = 0.5f * (zi + mi), X1i = -0.5f * (zr - mr);
    Xre[o0 + k] = X0r * sc; Xim[o0 + k] = X0i * sc;
    Xre[o1 + k] = X1r * sc; Xim[o1 + k] = X1i * sc;
  }
}

// ---------------- generic 2-plane tiled transpose (R x C -> C x R) ----------
__global__ __launch_bounds__(256) void transpose2(
    const float* __restrict__ s0, const float* __restrict__ s1,
    float* __restrict__ d0, float* __restrict__ d1, int R, int C) {
  __shared__ float tile[32][33];
  const float* src = blockIdx.z ? s1 : s0;
  float* dst = blockIdx.z ? d1 : d0;
  int c0 = blockIdx.x * 32, r0 = blockIdx.y * 32;
  int tx = threadIdx.x & 31, ty = threadIdx.x >> 5;
  for (int p = 0; p < 32; p += 8) {
    int r = r0 + ty + p, c = c0 + tx;
    tile[ty + p][tx] = (r < R && c < C) ? src[(size_t)r * C + c] : 0.f;
  }
  __syncthreads();
  for (int p = 0; p < 32; p += 8) {
    int r = c0 + ty + p, c = r0 + tx;
    if (r < C && c < R) dst[(size_t)r * R + c] = tile[tx][ty + p];
  }
}

// ---------------- Kernel C: per-frequency channel mix via MFMA (bf16x3) ------
typedef short  s8v  __attribute__((ext_vector_type(8)));
typedef float  f4v  __attribute__((ext_vector_type(4)));

__device__ __forceinline__ unsigned short f2bf_hi(float x) {
  unsigned u = __float_as_uint(x);
  unsigned r = (u + 0x7fffu + ((u >> 16) & 1u)) >> 16;   // RNE
  return (unsigned short)r;
}

// B-fragment LDS index: slab = (n>>4)*2 + (k>>5); L = (n&15) + ((k>>3)&3)*16; j = k&7
__device__ __forceinline__ int fbi(int k, int n) {
  return ((((n >> 4) * 2 + (k >> 5)) << 9) | (((n & 15) + (((k >> 3) & 3) << 4)) << 3) | (k & 7));
}
// A-fragment LDS index: slab = k>>5
__device__ __forceinline__ int fai(int k, int m) {
  return (((k >> 5) << 9) | (((m & 15) + (((k >> 3) & 3) << 4)) << 3) | (k & 7));
}

__global__ __launch_bounds__(256) void mix_mfma(
    const float* __restrict__ Xtr, const float* __restrict__ Xti,
    const float* __restrict__ Wr_g, const float* __restrict__ Wi_g,
    const float* __restrict__ tmr, const float* __restrict__ tmi,
    float* __restrict__ Yr_g, float* __restrict__ Yi_g) {
  __shared__ __align__(16) unsigned short BrH[4096], BrL[4096], BiH[4096], BiL[4096];
  __shared__ __align__(16) unsigned short ArH[1024], ArL[1024];
  __shared__ __align__(16) unsigned short AiH[1024], AiL[1024];
  __shared__ __align__(16) unsigned short AnH[1024], AnL[1024];  // -Ai
  __shared__ float tms[32];
  const int i   = blockIdx.x;
  const int tid = threadIdx.x;

  const float4* wr4 = (const float4*)(Wr_g + (size_t)i * 4096);
  const float4* wi4 = (const float4*)(Wi_g + (size_t)i * 4096);
#pragma unroll
  for (int it = 0; it < 4; ++it) {
    int f4 = it * 256 + tid;          // 0..1023
    float4 vr = wr4[f4];
    float4 vi = wi4[f4];
    int idx0 = f4 * 4;
    float er[4] = {vr.x, vr.y, vr.z, vr.w};
    float ei[4] = {vi.x, vi.y, vi.z, vi.w};
#pragma unroll
    for (int e = 0; e < 4; ++e) {
      int idx = idx0 + e;
      int k = idx >> 6, n = idx & 63;
      int a = fbi(k, n);
      unsigned short h = f2bf_hi(er[e]);
      float hf = __uint_as_float(((unsigned)h) << 16);
      BrH[a] = h; BrL[a] = f2bf_hi(er[e] - hf);
      h = f2bf_hi(ei[e]);
      hf = __uint_as_float(((unsigned)h) << 16);
      BiH[a] = h; BiL[a] = f2bf_hi(ei[e] - hf);
    }
  }
  {
    float4 vr = ((const float4*)(Xtr + (size_t)i * 1024))[tid];
    float4 vi = ((const float4*)(Xti + (size_t)i * 1024))[tid];
    float er[4] = {vr.x, vr.y, vr.z, vr.w};
    float ei[4] = {vi.x, vi.y, vi.z, vi.w};
    int idx0 = tid * 4;
#pragma unroll
    for (int e = 0; e < 4; ++e) {
      int idx = idx0 + e;
      int m = idx >> 6, k = idx & 63;
      int a = fai(k, m);
      unsigned short h = f2bf_hi(er[e]);
      float hf = __uint_as_float(((unsigned)h) << 16);
      ArH[a] = h; ArL[a] = f2bf_hi(er[e] - hf);
      h = f2bf_hi(ei[e]);
      hf = __uint_as_float(((unsigned)h) << 16);
      unsigned short l = f2bf_hi(ei[e] - __uint_as_float(((unsigned)h) << 16));
      AiH[a] = h; AiL[a] = l;
      AnH[a] = h ^ 0x8000u; AnL[a] = l ^ 0x8000u;
    }
  }
  if (tid < 16) {
    tms[tid]      = tmr[tid * M_ + i];
    tms[16 + tid] = tmi[tid * M_ + i];
  }
  __syncthreads();

  const int w = tid >> 6, L = tid & 63;
  const s8v* pArH = (const s8v*)ArH; const s8v* pArL = (const s8v*)ArL;
  const s8v* pAiH = (const s8v*)AiH; const s8v* pAiL = (const s8v*)AiL;
  const s8v* pAnH = (const s8v*)AnH; const s8v* pAnL = (const s8v*)AnL;
  const s8v* pBrH = (const s8v*)BrH; const s8v* pBrL = (const s8v*)BrL;
  const s8v* pBiH = (const s8v*)BiH; const s8v* pBiL = (const s8v*)BiL;

  f4v cr = {0.f, 0.f, 0.f, 0.f}, ci = {0.f, 0.f, 0.f, 0.f};
#pragma unroll
  for (int s = 0; s < 2; ++s) {
    s8v arh = pArH[s * 64 + L], arl = pArL[s * 64 + L];
    s8v aih = pAiH[s * 64 + L], ail = pAiL[s * 64 + L];
    s8v anh = pAnH[s * 64 + L], anl = pAnL[s * 64 + L];
    int bo = (w * 2 + s) * 64 + L;
    s8v brh = pBrH[bo], brl = pBrL[bo];
    s8v bih = pBiH[bo], bil = pBiL[bo];
    cr = __builtin_amdgcn_mfma_f32_16x16x32_bf16(arh, brh, cr, 0, 0, 0);
    cr = __builtin_amdgcn_mfma_f32_16x16x32_bf16(arh, brl, cr, 0, 0, 0);
    cr = __builtin_amdgcn_mfma_f32_16x16x32_bf16(arl, brh, cr, 0, 0, 0);
    cr = __builtin_amdgcn_mfma_f32_16x16x32_bf16(anh, bih, cr, 0, 0, 0);
    cr = __builtin_amdgcn_mfma_f32_16x16x32_bf16(anh, bil, cr, 0, 0, 0);
    cr = __builtin_amdgcn_mfma_f32_16x16x32_bf16(anl, bih, cr, 0, 0, 0);
    ci = __builtin_amdgcn_mfma_f32_16x16x32_bf16(arh, bih, ci, 0, 0, 0);
    ci = __builtin_amdgcn_mfma_f32_16x16x32_bf16(arh, bil, ci, 0, 0, 0);
    ci = __builtin_amdgcn_mfma_f32_16x16x32_bf16(arl, bih, ci, 0, 0, 0);
    ci = __builtin_amdgcn_mfma_f32_16x16x32_bf16(aih, brh, ci, 0, 0, 0);
    ci = __builtin_amdgcn_mfma_f32_16x16x32_bf16(aih, brl, ci, 0, 0, 0);
    ci = __builtin_amdgcn_mfma_f32_16x16x32_bf16(ail, brh, ci, 0, 0, 0);
  }

  const int n = (L & 15) + 16 * w;
  const int quad = L >> 4;
#pragma unroll
  for (int r = 0; r < 4; ++r) {
    int m = quad * 4 + r;
    float tr = tms[m], ti = tms[16 + m];
    float yr = tr * cr[r] - ti * ci[r];
    float yi = tr * ci[r] + ti * cr[r];
    size_t o = (size_t)i * 1024 + m * 64 + n;
    Yr_g[o] = yr;
    Yi_g[o] = yi;
  }
}

// ------- Kernel D: fused hermitian assemble + inverse FFT + direct store ----
// Z[k] = Y0ext[k] + i*Y1ext[k] with Yext hermitian extension of half-spectrum;
// z = IFFT_16384(Z) (no scale, norm='forward'); out[b,n,c0]=Re, out[b,n,c1]=Im.
__global__ __launch_bounds__(1024) void fft_inv_fused(
    const float* __restrict__ Ytr, const float* __restrict__ Yti,
    float* __restrict__ out) {
  __shared__ float sre[N_], sim[N_];    // 128 KiB
  int b, cp;
  decode_bc(blockIdx.x, b, cp);
  const int tid = threadIdx.x;
  size_t y0 = (size_t)(b * COUT + 2 * cp) * M_;
  size_t y1 = y0 + M_;
#pragma unroll
  for (int s = 0; s < 16; ++s) {
    int k = tid + 1024 * s;
    float Zr = 0.f, Zi = 0.f;
    if (k < M_) {
      float a0r = Ytr[y0 + k], a0i = Yti[y0 + k];
      float a1r = Ytr[y1 + k], a1i = Yti[y1 + k];
      Zr = a0r - a1i;                 // Y0[k] + i*Y1[k]
      Zi = a0i + a1r;
    }
    int m = N_ - k;
    if (k > 0 && m < M_) {
      float b0r = Ytr[y0 + m], b0i = Yti[y0 + m];
      float b1r = Ytr[y1 + m], b1i = Yti[y1 + m];
      // conj(Y0[m]) + i*conj(Y1[m])
      Zr += b0r + b1i;
      Zi += b1r - b0i;
    }
    int rr = SW((int)br14((unsigned)k));
    sre[rr] = Zr;
    sim[rr] = Zi;
  }
  __syncthreads();
  group16<1, 0>(sre, sim, tid); __syncthreads();
  group16<1, 4>(sre, sim, tid); __syncthreads();
  group16<1, 8>(sre, sim, tid); __syncthreads();
  stage12<1>(sre, sim, tid);    __syncthreads();
  stage13<1>(sre, sim, tid);    __syncthreads();
  float* ob = out + (size_t)b * N_ * COUT + 2 * cp;
#pragma unroll
  for (int s = 0; s < 16; ++s) {
    int n = tid + 1024 * s;
    int p = SW(n);
    *(float2*)(ob + (size_t)n * COUT) = make_float2(sre[p], sim[p]);
  }
}

extern "C" void kernel_launch(void* const* d_in, const int* in_sizes, int n_in,
                              void* d_out, int out_size, void* d_ws, size_t ws_size,
                              hipStream_t stream) {
  const float* x    = (const float*)d_in[0];
  const float* temb = (const float*)d_in[1];
  const float* wr   = (const float*)d_in[2];
  const float* wi   = (const float*)d_in[3];
  const float* dwr  = (const float*)d_in[4];
  const float* dwi  = (const float*)d_in[5];
  float* out = (float*)d_out;

  float* ws  = (float*)d_ws;
  float* tmr = ws;
  float* tmi = tmr + 32784;
  float* Xre = tmi + 32784;                // X (b,c,k) — later Yt (b,o,k)
  float* Xim = Xre + 2098176;
  float* Xtr = Xim + 2098176;              // Xt (k,b,c) — later Y (i,b,o)
  float* Xti = Xtr + 2098176;

  tmod_kernel<<<dim3((B_ * M_ + 3) / 4), 256, 0, stream>>>(temb, dwr, dwi, tmr, tmi);
  fft_fwd_fused<<<dim3(B_ * CIN / 2), 1024, 0, stream>>>(x, Xre, Xim);
  transpose2<<<dim3((M_ + 31) / 32, (B_ * CIN + 31) / 32, 2), 256, 0, stream>>>(
      Xre, Xim, Xtr, Xti, B_ * CIN, M_);
  mix_mfma<<<dim3(M_), 256, 0, stream>>>(Xtr, Xti, wr, wi, tmr, tmi, Xtr, Xti);
  transpose2<<<dim3((B_ * COUT + 31) / 32, (M_ + 31) / 32, 2), 256, 0, stream>>>(
      Xtr, Xti, Xre, Xim, M_, B_ * COUT);
  fft_inv_fused<<<dim3(B_ * COUT / 2), 1024, 0, stream>>>(Xre, Xim, out);
}